// Round 1
// 91.166 us; speedup vs baseline: 1.1604x; 1.1604x over previous
//
#include <hip/hip_runtime.h>
#include <hip/hip_bf16.h>
#include <math.h>

// Problem constants (fixed by the reference file): B=1, N=2048, V=1, H=W=128.
#define NMAX 2048
#define IMG_W 128
#define IMG_H 128
#define TILE 8            // 8x8 pixel tiles -> 256 blocks = 1 per CU
#define CAP  1024         // max survivors per tile (measured ~100; 10x margin)

// ---------------------------------------------------------------------------
// Single fused kernel, one block per 8x8 tile:
//  Phase 1 (fused preprocess+cull): each thread processes 8 gaussians fully
//    in registers; survivors appended (atomicAdd) to compact LDS AoS
//    (float4/float4/float2 -> 3 broadcast ds_reads in phase 3 instead of 10).
//  Phase 2: rank-counting sort of the M survivor keys (M ~ 100-200).
//  Phase 3 (NEW): chunked parallel compositing. Compositing weights are a
//    prefix product  w_j = a_j * prod_{k<j}(1-a_k), so the sorted list is
//    split into 4 contiguous chunks, one per wave (t = chunk*64 + pixel).
//    Each wave composites its chunk with local T starting at 1 (all 4 SIMDs
//    busy, ~M/4 serial iterations instead of M on a single wave), then a
//    small LDS exchange combines:
//      rgb = rgb0 + T0*(rgb1 + T1*(rgb2 + T2*rgb3)), same for depth.
//    Inner loop is branchless (al zeroed when culled) so it pipelines;
//    per-chunk early exit at local T<1e-5 is conservative vs the old global
//    exit (chunk contributions are bounded by local T).
// LDS: 16K+16K+8K (AoS) + 8K keys + 4K sidx + 5K combine + 4 = ~57 KB.
// ---------------------------------------------------------------------------
__global__ __launch_bounds__(256) void fused_render_kernel(
    const float* __restrict__ xyz, const float* __restrict__ feat,
    const float* __restrict__ scal, const float* __restrict__ rot,
    const float* __restrict__ opac, const float* __restrict__ c2w,
    const float* __restrict__ intr, const int* __restrict__ nearp,
    const int* __restrict__ farp, float* __restrict__ out, int N)
{
    __shared__ float4 sA[CAP];                 // u, v, ia, ib
    __shared__ float4 sB[CAP];                 // ic, op, cr, cg
    __shared__ float2 sC[CAP];                 // cb, z
    __shared__ unsigned long long keys[CAP];
    __shared__ int sidx[CAP];
    __shared__ float cT[256], cR[256], cG[256], cB[256], cD[256];
    __shared__ int cnt;

    const int t = threadIdx.x;
    if (t == 0) cnt = 0;
    __syncthreads();

    // ---- camera setup (uniform; folds to scalar ops) ----
    const float A00=c2w[0], A01=c2w[1], A02=c2w[2],  b0=c2w[3];
    const float A10=c2w[4], A11=c2w[5], A12=c2w[6],  b1=c2w[7];
    const float A20=c2w[8], A21=c2w[9], A22=c2w[10], b2=c2w[11];
    const float detA = A00*(A11*A22-A12*A21) - A01*(A10*A22-A12*A20)
                     + A02*(A10*A21-A11*A20);
    const float id = 1.0f/detA;
    const float R00 =  (A11*A22-A12*A21)*id;
    const float R01 = -(A01*A22-A02*A21)*id;
    const float R02 =  (A01*A12-A02*A11)*id;
    const float R10 = -(A10*A22-A12*A20)*id;
    const float R11 =  (A00*A22-A02*A20)*id;
    const float R12 = -(A00*A12-A02*A10)*id;
    const float R20 =  (A10*A21-A11*A20)*id;
    const float R21 = -(A00*A21-A01*A20)*id;
    const float R22 =  (A00*A11-A01*A10)*id;
    const float t0 = -(R00*b0 + R01*b1 + R02*b2);
    const float t1 = -(R10*b0 + R11*b1 + R12*b2);
    const float t2 = -(R20*b0 + R21*b1 + R22*b2);
    const float fx=intr[0], fy=intr[1], cx=intr[2], cy=intr[3];
    const float nearf = (float)nearp[0], farf = (float)farp[0];

    const int tilex = blockIdx.x & (IMG_W/TILE - 1);
    const int tiley = blockIdx.x / (IMG_W/TILE);
    const float tx0 = tilex*TILE + 0.5f, tx1 = tx0 + (TILE-1);
    const float ty0 = tiley*TILE + 0.5f, ty1 = ty0 + (TILE-1);

    // ---- phase 1: preprocess + cull + append survivors ----
    #pragma unroll
    for (int i = 0; i < NMAX/256; ++i) {
        const int g = i*256 + t;
        if (g >= N) continue;
        const float4 q4 = *(const float4*)(rot + g*4);
        float qw=q4.x, qx=q4.y, qy=q4.z, qz=q4.w;
        float iq = 1.0f/(sqrtf(qw*qw+qx*qx+qy*qy+qz*qz) + 1e-8f);
        qw*=iq; qx*=iq; qy*=iq; qz*=iq;
        float r00=1.f-2.f*(qy*qy+qz*qz), r01=2.f*(qx*qy-qw*qz), r02=2.f*(qx*qz+qw*qy);
        float r10=2.f*(qx*qy+qw*qz), r11=1.f-2.f*(qx*qx+qz*qz), r12=2.f*(qy*qz-qw*qx);
        float r20=2.f*(qx*qz-qw*qy), r21=2.f*(qy*qz+qw*qx), r22=1.f-2.f*(qx*qx+qy*qy);
        float s0=scal[g*3], s1=scal[g*3+1], s2=scal[g*3+2];
        float m00=r00*s0, m01=r01*s1, m02=r02*s2;
        float m10=r10*s0, m11=r11*s1, m12=r12*s2;
        float m20=r20*s0, m21=r21*s1, m22=r22*s2;
        // U3 = Rw @ M  (cov2d = (J U3)(J U3)^T)
        float u00=R00*m00+R01*m10+R02*m20, u01=R00*m01+R01*m11+R02*m21, u02=R00*m02+R01*m12+R02*m22;
        float u10=R10*m00+R11*m10+R12*m20, u11=R10*m01+R11*m11+R12*m21, u12=R10*m02+R11*m12+R12*m22;
        float u20=R20*m00+R21*m10+R22*m20, u21=R20*m01+R21*m11+R22*m21, u22=R20*m02+R21*m12+R22*m22;
        float x0=xyz[g*3], x1=xyz[g*3+1], x2=xyz[g*3+2];
        float p0=R00*x0+R01*x1+R02*x2+t0;
        float p1=R10*x0+R11*x1+R12*x2+t1;
        float p2=R20*x0+R21*x1+R22*x2+t2;
        float z = p2;
        float zs = fmaxf(z, 1e-4f);
        float invzs = 1.0f/zs;
        float u = fx*p0*invzs + cx;
        float v = fy*p1*invzs + cy;
        float j00 = fx*invzs, j02 = -fx*p0*invzs*invzs;
        float j11 = fy*invzs, j12 = -fy*p1*invzs*invzs;
        float T00=j00*u00+j02*u20, T01=j00*u01+j02*u21, T02=j00*u02+j02*u22;
        float T10=j11*u10+j12*u20, T11=j11*u11+j12*u21, T12=j11*u12+j12*u22;
        float a  = T00*T00+T01*T01+T02*T02 + 0.3f;
        float bb = T00*T10+T01*T11+T02*T12;
        float c  = T10*T10+T11*T11+T12*T12 + 0.3f;
        float dt = a*c - bb*bb;
        bool  vdet = dt > 1e-12f;
        float inv = 1.0f/(vdet ? dt : 1.0f);
        bool valid = (z > nearf) && (z < farf) && vdet;
        float op = valid ? opac[g] : 0.0f;

        // cull: alpha>=1/255 ellipse bbox vs tile (conic PD when valid)
        float tau = 2.0f*__logf(255.0f*op) + 0.02f;   // conservative eps
        if (tau <= 0.0f) continue;
        float ia =  c*inv, ib = -bb*inv, ic = a*inv;
        float detC = ia*ic - ib*ib;                   // = 1/det(cov2d) > 0
        float dci  = 1.0f/detC;
        float ru = sqrtf(tau * ic * dci);             // sqrt(tau*Sigma_xx)
        float rv = sqrtf(tau * ia * dci);             // sqrt(tau*Sigma_yy)
        if ((u + ru < tx0) || (u - ru > tx1) ||
            (v + rv < ty0) || (v - rv > ty1)) continue;

        int p = atomicAdd(&cnt, 1);
        if (p < CAP) {
            float cr = fmaxf(0.28209479177387814f*feat[g*3+0]+0.5f, 0.0f);
            float cg = fmaxf(0.28209479177387814f*feat[g*3+1]+0.5f, 0.0f);
            float cb = fmaxf(0.28209479177387814f*feat[g*3+2]+0.5f, 0.0f);
            sA[p] = make_float4(u, v, ia, ib);
            sB[p] = make_float4(ic, op, cr, cg);
            sC[p] = make_float2(cb, z);
            keys[p] = ((unsigned long long)__float_as_uint(z) << 21)
                    | ((unsigned long long)g << 10)
                    | (unsigned long long)p;
        }
    }
    __syncthreads();
    const int M = min(cnt, CAP);

    // ---- phase 2: stable rank-counting sort of survivor keys ----
    for (int s = t; s < M; s += 256) {
        const unsigned long long k = keys[s];
        int rank = 0;
        for (int j = 0; j < M; ++j) rank += (keys[j] < k) ? 1 : 0;
        sidx[rank] = (int)(k & (CAP-1));
    }
    __syncthreads();

    // ---- phase 3: chunked front-to-back compositing, all 4 waves ----
    // thread t = chunk*64 + pixel; chunk w composites sorted range
    // [w*Mc, min(M,(w+1)*Mc)) with local T starting at 1.
    {
        const int p = t & 63;                 // pixel within tile
        const int w = t >> 6;                 // chunk = wave id
        const int Mc = (M + 3) >> 2;
        const int j0 = w * Mc;
        const int j1 = min(M, j0 + Mc);
        const int x = tilex*TILE + (p & (TILE-1));
        const int y = tiley*TILE + (p / TILE);
        const float px = x + 0.5f, py = y + 0.5f;
        float T = 1.0f, rr = 0.f, gg = 0.f, bbv = 0.f, dd = 0.f;
        for (int j = j0; j < j1; ++j) {
            const int s = sidx[j];            // uniform -> LDS broadcast
            const float4 A  = sA[s];          // u, v, ia, ib
            const float4 Bv = sB[s];          // ic, op, cr, cg
            const float2 Cv = sC[s];          // cb, z
            float dx = px - A.x, dy = py - A.y;
            float pw = -0.5f*(A.z*dx*dx + Bv.x*dy*dy) - A.w*dx*dy;
            float al = fminf(Bv.y*__expf(fminf(pw, 0.0f)), 0.99f);
            // branchless keep: zero alpha if culled -> loop body pipelines
            al = (pw <= 0.0f && al >= (1.0f/255.0f)) ? al : 0.0f;
            float wgt = T * al;
            rr  += wgt * Bv.z;
            gg  += wgt * Bv.w;
            bbv += wgt * Cv.x;
            dd  += wgt * Cv.y;
            T *= (1.0f - al);
            if (T < 1e-5f) break;             // chunk-local, conservative
        }
        cT[t] = T; cR[t] = rr; cG[t] = gg; cB[t] = bbv; cD[t] = dd;
    }
    __syncthreads();

    // ---- combine the 4 chunk partials (prefix-transmittance) + store ----
    if (t < TILE*TILE) {
        const int p = t;
        const float T0 = cT[p], T1 = cT[p+64], T2 = cT[p+128];
        const float r = cR[p] + T0*(cR[p+ 64] + T1*(cR[p+128] + T2*cR[p+192]));
        const float g = cG[p] + T0*(cG[p+ 64] + T1*(cG[p+128] + T2*cG[p+192]));
        const float b = cB[p] + T0*(cB[p+ 64] + T1*(cB[p+128] + T2*cB[p+192]));
        const float d = cD[p] + T0*(cD[p+ 64] + T1*(cD[p+128] + T2*cD[p+192]));
        const int x = tilex*TILE + (p & (TILE-1));
        const int y = tiley*TILE + (p / TILE);
        const int HW = IMG_W*IMG_H;
        const int pix = y*IMG_W + x;
        out[0*HW+pix] = r;
        out[1*HW+pix] = g;
        out[2*HW+pix] = b;
        out[3*HW+pix] = d;
    }
}

extern "C" void kernel_launch(void* const* d_in, const int* in_sizes, int n_in,
                              void* d_out, int out_size, void* d_ws, size_t ws_size,
                              hipStream_t stream) {
    const float* xyz  = (const float*)d_in[0];
    const float* feat = (const float*)d_in[1];
    const float* scal = (const float*)d_in[2];
    const float* rot  = (const float*)d_in[3];
    const float* opac = (const float*)d_in[4];
    const float* c2w  = (const float*)d_in[5];
    const float* intr = (const float*)d_in[6];
    const int*   nearp = (const int*)d_in[10];
    const int*   farp  = (const int*)d_in[11];
    float* out = (float*)d_out;
    const int N = in_sizes[0] / 3;

    const int ntiles = (IMG_W/TILE) * (IMG_H/TILE);  // 256 blocks
    fused_render_kernel<<<ntiles, 256, 0, stream>>>(
        xyz, feat, scal, rot, opac, c2w, intr, nearp, farp, out, N);
}

// Round 2
// 84.078 us; speedup vs baseline: 1.2582x; 1.0843x over previous
//
#include <hip/hip_runtime.h>
#include <hip/hip_bf16.h>
#include <math.h>

// Problem constants (fixed by the reference file): B=1, N=2048, V=1, H=W=128.
#define NMAX 2048
#define IMG_W 128
#define IMG_H 128
#define TILE 8            // 8x8 pixel tiles -> 256 blocks = 1 per CU
#define CAP  1024         // max survivors per tile (measured ~100; 10x margin)
#define BLK  512          // 8 waves = 2 waves/SIMD for latency hiding
#define NCHUNK 8          // compositing chunks (= waves)

// ---------------------------------------------------------------------------
// Single fused kernel, one block per 8x8 tile, 512 threads (2 waves/SIMD so
// dependent-chain + LDS/exp latency is hidden by wave interleave in every
// phase; 256-thread version had 1 wave/SIMD = zero hiding).
//  Phase 1 (fused preprocess+cull): each thread processes 4 gaussians fully
//    in registers; survivors appended (atomicAdd) to compact LDS AoS
//    (float4/float4/float2 -> 3 broadcast ds_reads in phase 3).
//  Phase 2: rank-counting sort of the M survivor keys (M ~ 100-200).
//  Phase 3: chunked parallel compositing. Compositing weights are a prefix
//    product w_j = a_j * prod_{k<j}(1-a_k); the sorted list splits into 8
//    contiguous chunks, one per wave (t = chunk*64 + pixel). Each wave
//    composites its chunk with local T starting at 1 (~M/8 ~ 13 serial
//    iterations). Branchless body, no early-exit break -> unrolls x4 and
//    pipelines. LDS combine:
//      rgb = sum_w (prod_{w'<w} T_w') * rgb_w   (exact prefix algebra).
// LDS: 16K+16K+8K (AoS) + 8K keys + 4K sidx + 10K combine + 4 = ~62 KB.
// ---------------------------------------------------------------------------
__global__ __launch_bounds__(BLK) void fused_render_kernel(
    const float* __restrict__ xyz, const float* __restrict__ feat,
    const float* __restrict__ scal, const float* __restrict__ rot,
    const float* __restrict__ opac, const float* __restrict__ c2w,
    const float* __restrict__ intr, const int* __restrict__ nearp,
    const int* __restrict__ farp, float* __restrict__ out, int N)
{
    __shared__ float4 sA[CAP];                 // u, v, ia, ib
    __shared__ float4 sB[CAP];                 // ic, op, cr, cg
    __shared__ float2 sC[CAP];                 // cb, z
    __shared__ unsigned long long keys[CAP];
    __shared__ int sidx[CAP];
    __shared__ float cT[BLK], cR[BLK], cG[BLK], cB[BLK], cD[BLK];
    __shared__ int cnt;

    const int t = threadIdx.x;
    if (t == 0) cnt = 0;
    __syncthreads();

    // ---- camera setup (uniform; folds to scalar ops) ----
    const float A00=c2w[0], A01=c2w[1], A02=c2w[2],  b0=c2w[3];
    const float A10=c2w[4], A11=c2w[5], A12=c2w[6],  b1=c2w[7];
    const float A20=c2w[8], A21=c2w[9], A22=c2w[10], b2=c2w[11];
    const float detA = A00*(A11*A22-A12*A21) - A01*(A10*A22-A12*A20)
                     + A02*(A10*A21-A11*A20);
    const float id = 1.0f/detA;
    const float R00 =  (A11*A22-A12*A21)*id;
    const float R01 = -(A01*A22-A02*A21)*id;
    const float R02 =  (A01*A12-A02*A11)*id;
    const float R10 = -(A10*A22-A12*A20)*id;
    const float R11 =  (A00*A22-A02*A20)*id;
    const float R12 = -(A00*A12-A02*A10)*id;
    const float R20 =  (A10*A21-A11*A20)*id;
    const float R21 = -(A00*A21-A01*A20)*id;
    const float R22 =  (A00*A11-A01*A10)*id;
    const float t0 = -(R00*b0 + R01*b1 + R02*b2);
    const float t1 = -(R10*b0 + R11*b1 + R12*b2);
    const float t2 = -(R20*b0 + R21*b1 + R22*b2);
    const float fx=intr[0], fy=intr[1], cx=intr[2], cy=intr[3];
    const float nearf = (float)nearp[0], farf = (float)farp[0];

    const int tilex = blockIdx.x & (IMG_W/TILE - 1);
    const int tiley = blockIdx.x / (IMG_W/TILE);
    const float tx0 = tilex*TILE + 0.5f, tx1 = tx0 + (TILE-1);
    const float ty0 = tiley*TILE + 0.5f, ty1 = ty0 + (TILE-1);

    // ---- phase 1: preprocess + cull + append survivors ----
    #pragma unroll
    for (int i = 0; i < NMAX/BLK; ++i) {
        const int g = i*BLK + t;
        if (g >= N) continue;
        const float4 q4 = *(const float4*)(rot + g*4);
        float qw=q4.x, qx=q4.y, qy=q4.z, qz=q4.w;
        float iq = 1.0f/(sqrtf(qw*qw+qx*qx+qy*qy+qz*qz) + 1e-8f);
        qw*=iq; qx*=iq; qy*=iq; qz*=iq;
        float r00=1.f-2.f*(qy*qy+qz*qz), r01=2.f*(qx*qy-qw*qz), r02=2.f*(qx*qz+qw*qy);
        float r10=2.f*(qx*qy+qw*qz), r11=1.f-2.f*(qx*qx+qz*qz), r12=2.f*(qy*qz-qw*qx);
        float r20=2.f*(qx*qz-qw*qy), r21=2.f*(qy*qz+qw*qx), r22=1.f-2.f*(qx*qx+qy*qy);
        float s0=scal[g*3], s1=scal[g*3+1], s2=scal[g*3+2];
        float m00=r00*s0, m01=r01*s1, m02=r02*s2;
        float m10=r10*s0, m11=r11*s1, m12=r12*s2;
        float m20=r20*s0, m21=r21*s1, m22=r22*s2;
        // U3 = Rw @ M  (cov2d = (J U3)(J U3)^T)
        float u00=R00*m00+R01*m10+R02*m20, u01=R00*m01+R01*m11+R02*m21, u02=R00*m02+R01*m12+R02*m22;
        float u10=R10*m00+R11*m10+R12*m20, u11=R10*m01+R11*m11+R12*m21, u12=R10*m02+R11*m12+R12*m22;
        float u20=R20*m00+R21*m10+R22*m20, u21=R20*m01+R21*m11+R22*m21, u22=R20*m02+R21*m12+R22*m22;
        float x0=xyz[g*3], x1=xyz[g*3+1], x2=xyz[g*3+2];
        float p0=R00*x0+R01*x1+R02*x2+t0;
        float p1=R10*x0+R11*x1+R12*x2+t1;
        float p2=R20*x0+R21*x1+R22*x2+t2;
        float z = p2;
        float zs = fmaxf(z, 1e-4f);
        float invzs = 1.0f/zs;
        float u = fx*p0*invzs + cx;
        float v = fy*p1*invzs + cy;
        float j00 = fx*invzs, j02 = -fx*p0*invzs*invzs;
        float j11 = fy*invzs, j12 = -fy*p1*invzs*invzs;
        float T00=j00*u00+j02*u20, T01=j00*u01+j02*u21, T02=j00*u02+j02*u22;
        float T10=j11*u10+j12*u20, T11=j11*u11+j12*u21, T12=j11*u12+j12*u22;
        float a  = T00*T00+T01*T01+T02*T02 + 0.3f;
        float bb = T00*T10+T01*T11+T02*T12;
        float c  = T10*T10+T11*T11+T12*T12 + 0.3f;
        float dt = a*c - bb*bb;
        bool  vdet = dt > 1e-12f;
        float inv = 1.0f/(vdet ? dt : 1.0f);
        bool valid = (z > nearf) && (z < farf) && vdet;
        float op = valid ? opac[g] : 0.0f;

        // cull: alpha>=1/255 ellipse bbox vs tile (conic PD when valid)
        float tau = 2.0f*__logf(255.0f*op) + 0.02f;   // conservative eps
        if (tau <= 0.0f) continue;
        float ia =  c*inv, ib = -bb*inv, ic = a*inv;
        float detC = ia*ic - ib*ib;                   // = 1/det(cov2d) > 0
        float dci  = 1.0f/detC;
        float ru = sqrtf(tau * ic * dci);             // sqrt(tau*Sigma_xx)
        float rv = sqrtf(tau * ia * dci);             // sqrt(tau*Sigma_yy)
        if ((u + ru < tx0) || (u - ru > tx1) ||
            (v + rv < ty0) || (v - rv > ty1)) continue;

        int p = atomicAdd(&cnt, 1);
        if (p < CAP) {
            float cr = fmaxf(0.28209479177387814f*feat[g*3+0]+0.5f, 0.0f);
            float cg = fmaxf(0.28209479177387814f*feat[g*3+1]+0.5f, 0.0f);
            float cb = fmaxf(0.28209479177387814f*feat[g*3+2]+0.5f, 0.0f);
            sA[p] = make_float4(u, v, ia, ib);
            sB[p] = make_float4(ic, op, cr, cg);
            sC[p] = make_float2(cb, z);
            keys[p] = ((unsigned long long)__float_as_uint(z) << 21)
                    | ((unsigned long long)g << 10)
                    | (unsigned long long)p;
        }
    }
    __syncthreads();
    const int M = min(cnt, CAP);

    // ---- phase 2: stable rank-counting sort of survivor keys ----
    for (int s = t; s < M; s += BLK) {
        const unsigned long long k = keys[s];
        int rank = 0;
        for (int j = 0; j < M; ++j) rank += (keys[j] < k) ? 1 : 0;
        sidx[rank] = (int)(k & (CAP-1));
    }
    __syncthreads();

    // ---- phase 3: chunked front-to-back compositing, all 8 waves ----
    // thread t = chunk*64 + pixel; chunk w composites sorted range
    // [w*Mc, min(M,(w+1)*Mc)) with local T starting at 1.
    {
        const int p = t & 63;                 // pixel within tile
        const int w = t >> 6;                 // chunk = wave id
        const int Mc = (M + NCHUNK-1) / NCHUNK;
        const int j0 = w * Mc;
        const int j1 = min(M, j0 + Mc);
        const int x = tilex*TILE + (p & (TILE-1));
        const int y = tiley*TILE + (p / TILE);
        const float px = x + 0.5f, py = y + 0.5f;
        float T = 1.0f, rr = 0.f, gg = 0.f, bbv = 0.f, dd = 0.f;
        #pragma unroll 4
        for (int j = j0; j < j1; ++j) {
            const int s = sidx[j];            // uniform -> LDS broadcast
            const float4 A  = sA[s];          // u, v, ia, ib
            const float4 Bv = sB[s];          // ic, op, cr, cg
            const float2 Cv = sC[s];          // cb, z
            float dx = px - A.x, dy = py - A.y;
            float pw = -0.5f*(A.z*dx*dx + Bv.x*dy*dy) - A.w*dx*dy;
            float al = fminf(Bv.y*__expf(fminf(pw, 0.0f)), 0.99f);
            // branchless keep: zero alpha if culled -> loop body pipelines
            al = (pw <= 0.0f && al >= (1.0f/255.0f)) ? al : 0.0f;
            float wgt = T * al;
            rr  += wgt * Bv.z;
            gg  += wgt * Bv.w;
            bbv += wgt * Cv.x;
            dd  += wgt * Cv.y;
            T *= (1.0f - al);
        }
        cT[t] = T; cR[t] = rr; cG[t] = gg; cB[t] = bbv; cD[t] = dd;
    }
    __syncthreads();

    // ---- combine the 8 chunk partials (prefix-transmittance) + store ----
    if (t < TILE*TILE) {
        float Tacc = 1.0f, r = 0.f, g = 0.f, b = 0.f, d = 0.f;
        #pragma unroll
        for (int w = 0; w < NCHUNK; ++w) {
            const int idx = w*64 + t;
            r += Tacc * cR[idx];
            g += Tacc * cG[idx];
            b += Tacc * cB[idx];
            d += Tacc * cD[idx];
            Tacc *= cT[idx];
        }
        const int x = tilex*TILE + (t & (TILE-1));
        const int y = tiley*TILE + (t / TILE);
        const int HW = IMG_W*IMG_H;
        const int pix = y*IMG_W + x;
        out[0*HW+pix] = r;
        out[1*HW+pix] = g;
        out[2*HW+pix] = b;
        out[3*HW+pix] = d;
    }
}

extern "C" void kernel_launch(void* const* d_in, const int* in_sizes, int n_in,
                              void* d_out, int out_size, void* d_ws, size_t ws_size,
                              hipStream_t stream) {
    const float* xyz  = (const float*)d_in[0];
    const float* feat = (const float*)d_in[1];
    const float* scal = (const float*)d_in[2];
    const float* rot  = (const float*)d_in[3];
    const float* opac = (const float*)d_in[4];
    const float* c2w  = (const float*)d_in[5];
    const float* intr = (const float*)d_in[6];
    const int*   nearp = (const int*)d_in[10];
    const int*   farp  = (const int*)d_in[11];
    float* out = (float*)d_out;
    const int N = in_sizes[0] / 3;

    const int ntiles = (IMG_W/TILE) * (IMG_H/TILE);  // 256 blocks
    fused_render_kernel<<<ntiles, BLK, 0, stream>>>(
        xyz, feat, scal, rot, opac, c2w, intr, nearp, farp, out, N);
}